// Round 4
// baseline (603.649 us; speedup 1.0000x reference)
//
#include <hip/hip_runtime.h>
#include <math.h>

typedef long long I64;

// ---- problem constants ----
#define NB    8
#define NTOK  576
#define DIM   1024
#define NMASK 64
#define HMASK 384
#define WMASK 384
#define QDIM  4096
#define HDIM  1024
#define KREG  32
#define CCTX  128
#define GH    24
#define GW    24
#define GNUM  576

// ---- output layout (floats) ----
#define OFF_VIS 0
#define OFF_REG 1318912
#define OFF_CTX 1581056
#define OFF_BG  2629632
#define OFF_PP  2637824
#define OFF_RW  2642432
#define OFF_SEL 2647040
#define OFF_GV  2648064

// ---- workspace layout (floats) ----
#define WS_BS   0          // B*M*576 block sums
#define WS_NMAT 294912     // B*32*576 normalized masks
#define WS_SCK  442368     // B*32 scores_k
#define WS_H1   442624     // B*32*1024 silu hidden
#define WS_Q    704768     // B*1024 question row
#define WS_RS   712960     // B*576 routing scores
#define WS_GV   717568     // B grounding_valid
#define WS_PP   722184     // B*576 patch prior
#define WS_RSP  726792     // B*576*8 routing score partials
#define WS_CS   763656     // B*1024 token colsum

#define BS_BLOCKS (NB * NMASK * 24)   // 12288

// ======================== K1: block sums (coalesced) + fused q-row ========================
// blocks [0, BS_BLOCKS): one per (mask, 16-row band). 384 threads.
//   thread t sums float4 indices {t, t+384, t+768, t+1152} -> 1KB/wave contiguous.
//   fi = t + 384j -> row = t/96 + 4j, col4 = t%96 -> all 4 in block (t%96)/4, rows covered {0..3}+{0,4,8,12}.
// blocks [BS_BLOCKS, +128): q = qe @ Wq + bq, 64-lane coalesced, 6 i-groups.
__global__ __launch_bounds__(384) void k_bsq(const float* __restrict__ masks,
                                             const float* __restrict__ qe,
                                             const float* __restrict__ Wq,
                                             const float* __restrict__ bq,
                                             float* __restrict__ ws) {
  int gid = blockIdx.x;
  int t = threadIdx.x;
  __shared__ float sm[4][96];
  __shared__ float sp[6][64];
  if (gid < BS_BLOCKS) {
    int yband = gid % 24;
    int bm = gid / 24;
    const float4* src = (const float4*)(masks + (I64)bm * (HMASK * WMASK) + (I64)yband * 16 * WMASK);
    float4 s4 = src[t];
    float4 v1 = src[t + 384];
    float4 v2 = src[t + 768];
    float4 v3 = src[t + 1152];
    s4.x += v1.x; s4.y += v1.y; s4.z += v1.z; s4.w += v1.w;
    s4.x += v2.x; s4.y += v2.y; s4.z += v2.z; s4.w += v2.w;
    s4.x += v3.x; s4.y += v3.y; s4.z += v3.z; s4.w += v3.w;
    float s = (s4.x + s4.y) + (s4.z + s4.w);
    sm[t / 96][t % 96] = s;
    __syncthreads();
    if (t < 24) {
      float tt = 0.f;
      #pragma unroll
      for (int rg = 0; rg < 4; ++rg)
        #pragma unroll
        for (int c = 0; c < 4; ++c) tt += sm[rg][t * 4 + c];
      ws[WS_BS + (I64)bm * GNUM + yband * 24 + t] = tt;
    }
  } else {
    int q = gid - BS_BLOCKS;          // 0..127
    int b = q >> 4, qb = q & 15;      // 16 col-blocks of 64
    int dl = t & 63, ig = t >> 6;     // 6 i-groups
    int d = qb * 64 + dl;
    const float* qrow = qe + (I64)b * QDIM;
    float acc = 0.f;
    for (int i = ig; i < QDIM; i += 6)
      acc = fmaf(qrow[i], Wq[(I64)i * HDIM + d], acc);
    sp[ig][dl] = acc;
    __syncthreads();
    if (t < 64) {
      float s2 = ((sp[0][t] + sp[1][t]) + (sp[2][t] + sp[3][t])) + (sp[4][t] + sp[5][t]);
      ws[WS_Q + (I64)b * HDIM + qb * 64 + t] = s2 + bq[qb * 64 + t];
    }
  }
}

// ======================== K2: per-batch small ops (LDS-staged) ========================
#define MGPAD 580
__global__ __launch_bounds__(256) void k_perbatch(
    const float* __restrict__ bs, const float* __restrict__ scores,
    const float* __restrict__ W1, const float* __restrict__ b1,
    float* __restrict__ ws, float* __restrict__ out) {
  int b = blockIdx.x;
  int t = threadIdx.x;
  __shared__ float s_mg[KREG][MGPAD];
  __shared__ float s_sc[NMASK];
  __shared__ float s_msum[NMASK];
  __shared__ int   s_order[NMASK];
  __shared__ float s_sck[KREG];
  __shared__ int   s_valid[KREG];
  __shared__ int   s_midx[KREG];
  __shared__ float s_rowsum[KREG];
  __shared__ float s_pp[GNUM];
  __shared__ float s_geom[KREG][5];
  __shared__ float s_red[64];
  __shared__ int   s_gv;
  __shared__ float s_ppsum;

  {
    int m = t >> 2, q = t & 3;
    const float4* p = (const float4*)(bs + ((I64)b * NMASK + m) * GNUM) + q * 36;
    float s = 0.f;
    #pragma unroll 4
    for (int j = 0; j < 36; ++j) {
      float4 v = p[j];
      s += v.x; s += v.y; s += v.z; s += v.w;
    }
    s += __shfl_xor(s, 1);
    s += __shfl_xor(s, 2);
    if (q == 0) s_msum[m] = s;
  }
  if (t < NMASK) s_sc[t] = scores[b * NMASK + t];
  __syncthreads();
  if (t == 0) {
    int g = 0;
    for (int m = 0; m < NMASK; ++m) g |= (s_msum[m] > 0.f) ? 1 : 0;
    s_gv = g;
  }
  if (t < NMASK) {
    float v = s_sc[t];
    int r = 0;
    for (int j = 0; j < NMASK; ++j) {
      float vj = s_sc[j];
      r += (vj > v) || (vj == v && j < t);
    }
    s_order[r] = t;
  }
  __syncthreads();
  const int gv = s_gv;
  if (t < KREG) {
    int m = s_order[t];
    float sc = s_sc[m];
    int valid = (sc >= 0.5f) ? 1 : 0;
    s_midx[t] = m;
    s_valid[t] = valid;
    float sck = gv ? (valid ? sc : 0.f) : 1.f;
    s_sck[t] = sck;
    ws[WS_SCK + b * KREG + t] = sck;
  }
  __syncthreads();
  {
    int k = t >> 3, sub = t & 7;
    const float inv256 = 1.f / 256.f;
    const float invN = 1.f / 576.f;
    float scale = gv ? (s_valid[k] ? inv256 : 0.f) : 0.f;
    float addv  = gv ? 0.f : invN;
    const float4* src = (const float4*)(bs + ((I64)b * NMASK + s_midx[k]) * GNUM) + sub * 18;
    float* dst = &s_mg[k][sub * 72];
    #pragma unroll 3
    for (int j = 0; j < 18; ++j) {
      float4 v = src[j];
      v.x = v.x * scale + addv;
      v.y = v.y * scale + addv;
      v.z = v.z * scale + addv;
      v.w = v.w * scale + addv;
      *(float4*)(dst + j * 4) = v;
    }
  }
  __syncthreads();
  {
    int k = t >> 3, sub = t & 7;
    float part = 0.f;
    for (int n = sub; n < GNUM; n += 8) part += fmaxf(s_mg[k][n], 0.f);
    part += __shfl_xor(part, 1);
    part += __shfl_xor(part, 2);
    part += __shfl_xor(part, 4);
    if (sub == 0) s_rowsum[k] = part;
  }
  __syncthreads();
  for (int idx = t; idx < KREG * GNUM; idx += 256) {
    int k = idx / GNUM, n = idx - k * GNUM;
    float v = fmaxf(s_mg[k][n], 0.f);
    ws[WS_NMAT + ((I64)b * KREG + k) * GNUM + n] = v / fmaxf(s_rowsum[k], 1e-6f);
  }
  for (int n = t; n < GNUM; n += 256) {
    float raw = 0.f;
    #pragma unroll
    for (int k = 0; k < KREG; ++k) raw = fmaf(s_mg[k][n], s_sck[k], raw);
    s_pp[n] = fmaxf(raw, 0.f);
  }
  __syncthreads();
  if (t < 64) {
    float s = 0.f;
    for (int n = t; n < GNUM; n += 64) s += s_pp[n];
    s_red[t] = s;
  }
  __syncthreads();
  if (t == 0) {
    float s = 0.f;
    for (int i = 0; i < 64; ++i) s += s_red[i];
    s_ppsum = s;
  }
  __syncthreads();
  {
    const float invN = 1.f / 576.f;
    float den = fmaxf(s_ppsum, 1e-6f);
    for (int n = t; n < GNUM; n += 256) {
      float v = gv ? (s_pp[n] / den) : invN;
      ws[WS_PP + b * GNUM + n] = v;
      out[OFF_PP + b * GNUM + n] = v;
    }
  }
  {
    int k = t >> 3, sub = t & 7;
    unsigned colmask = 0u;
    int ymin = GH, ymax = -1, cnt = 0;
    #pragma unroll
    for (int yy = 0; yy < 3; ++yy) {
      int y = sub * 3 + yy;
      unsigned rowm = 0u;
      for (int x = 0; x < GW; ++x)
        if (s_mg[k][y * GW + x] > 0.05f) rowm |= (1u << x);
      if (rowm) { if (y < ymin) ymin = y; if (y > ymax) ymax = y; }
      colmask |= rowm;
      cnt += __popc(rowm);
    }
    #pragma unroll
    for (int off = 1; off < 8; off <<= 1) {
      colmask |= (unsigned)__shfl_xor((int)colmask, off);
      cnt += __shfl_xor(cnt, off);
      int o1 = __shfl_xor(ymin, off); ymin = (o1 < ymin) ? o1 : ymin;
      int o2 = __shfl_xor(ymax, off); ymax = (o2 > ymax) ? o2 : ymax;
    }
    if (sub == 0) {
      float g0, g1, g2, g3, g4;
      if (cnt > 0) {
        int xmin = __ffs(colmask) - 1;
        int xmax = 31 - __clz(colmask);
        g0 = (float)xmin / 23.f;
        g1 = (float)ymin / 23.f;
        g2 = (float)xmax / 23.f;
        g3 = (float)ymax / 23.f;
        g4 = (float)cnt / 576.f;
      } else { g0 = g1 = g2 = g3 = g4 = 0.f; }
      s_geom[k][0] = g0; s_geom[k][1] = g1; s_geom[k][2] = g2;
      s_geom[k][3] = g3; s_geom[k][4] = g4;
    }
  }
  __syncthreads();
  for (int idx = t; idx < KREG * HDIM; idx += 256) {
    int k = idx >> 10, j = idx & 1023;
    float x = 0.f;
    #pragma unroll
    for (int i = 0; i < 5; ++i) x += s_geom[k][i] * W1[i * HDIM + j];
    x += b1[j];
    float sg = 1.f / (1.f + expf(-x));
    ws[WS_H1 + ((I64)b * KREG + k) * HDIM + j] = x * sg;
  }
  if (t == 0) {
    float g = gv ? 1.f : 0.f;
    ws[WS_GV + b] = g;
    out[OFF_GV + b] = g;
  }
}

// ======================== K4: region tokens + colsum (512 thr, 4 range-quarters) ========================
// grid: 512 = 8b x 8kg(4 regions) x 8dg(128 cols); 512 threads = 128 d-lanes x 4 quarters
__global__ __launch_bounds__(512) void k_region(
    const float* __restrict__ pt, const float* __restrict__ W2,
    const float* __restrict__ b2, const float* __restrict__ te,
    float* __restrict__ ws, float* __restrict__ out) {
  int blk = blockIdx.x;
  int b = blk >> 6, kg = (blk >> 3) & 7, dg = blk & 7;
  int t = threadIdx.x;
  int dl = t & 127;
  int qh = t >> 7;                 // 0..3
  int d = dg * 128 + dl;
  const float* nmb = ws + WS_NMAT + ((I64)b * KREG + kg * 4) * GNUM;
  const float* h1b = ws + WS_H1 + ((I64)b * KREG + kg * 4) * HDIM;
  float accP[4] = {0, 0, 0, 0};
  float accG[4] = {0, 0, 0, 0};
  float accS = 0.f;
  int n0 = qh * 144, n1 = n0 + 144;
  for (int n = n0; n < n1; ++n) {
    float p = pt[((I64)b * NTOK + n) * DIM + d];
    accS += p;
    #pragma unroll
    for (int kk = 0; kk < 4; ++kk)
      accP[kk] = fmaf(nmb[kk * GNUM + n], p, accP[kk]);
  }
  int j0 = qh * 256, j1 = j0 + 256;
  for (int j = j0; j < j1; ++j) {
    float wv = W2[(I64)j * DIM + d];
    #pragma unroll
    for (int kk = 0; kk < 4; ++kk)
      accG[kk] = fmaf(h1b[kk * HDIM + j], wv, accG[kk]);
  }
  __shared__ float cmbP[4][4][128];
  __shared__ float cmbG[4][4][128];
  __shared__ float cmbS[4][128];
  #pragma unroll
  for (int kk = 0; kk < 4; ++kk) {
    cmbP[qh][kk][dl] = accP[kk];
    cmbG[qh][kk][dl] = accG[kk];
  }
  cmbS[qh][dl] = accS;
  __syncthreads();
  if (qh == 0) {
    float bb = b2[d], t0 = te[d];
    #pragma unroll
    for (int kk = 0; kk < 4; ++kk) {
      int k = kg * 4 + kk;
      float P = (cmbP[0][kk][dl] + cmbP[1][kk][dl]) + (cmbP[2][kk][dl] + cmbP[3][kk][dl]);
      float G = (cmbG[0][kk][dl] + cmbG[1][kk][dl]) + (cmbG[2][kk][dl] + cmbG[3][kk][dl]);
      float val = P * ws[WS_SCK + b * KREG + k] + G + bb + t0;
      out[OFF_REG + ((I64)b * KREG + k) * DIM + d] = val;
      out[OFF_VIS + ((I64)b * 161 + k) * DIM + d] = val;
    }
    if (kg == 0)
      ws[WS_CS + (I64)b * DIM + d] =
          (cmbS[0][dl] + cmbS[1][dl]) + (cmbS[2][dl] + cmbS[3][dl]);
  }
}

// ======================== K5: fused hid GEMM ========================
#define BM 48
#define BN 128
#define BK 32
#define KSTEPS (DIM / BK)
__global__ __launch_bounds__(256) void k_hid2(
    const float* __restrict__ pt, const float* __restrict__ Wv,
    const float* __restrict__ bv, const float* __restrict__ Wp,
    const float* __restrict__ bp, const float* __restrict__ Wo,
    float* __restrict__ ws) {
  int blk = blockIdx.x;
  int b  = blk / 96;
  int r  = blk % 96;
  int tt = r >> 3;
  int ct = r & 7;
  int n0 = tt * BM;
  int col0 = ct * BN;
  int t = threadIdx.x;
  int tcol = t & 31;
  int trow = t >> 5;

  __shared__ float sA[2][BK][BM];
  __shared__ float sW[2][BK][BN];

  float acc[6][4];
  #pragma unroll
  for (int i = 0; i < 6; ++i)
    #pragma unroll
    for (int j = 0; j < 4; ++j) acc[i][j] = 0.f;

  int a_tok = t >> 2, a_q = t & 3;
  const I64 a_row = ((I64)b * NTOK + n0 + a_tok) * DIM;
  int w_r = t >> 3, w_c = t & 7;
  const float* w_base = Wv + (I64)w_r * HDIM + col0;

  float4 a0 = {0,0,0,0}, a1 = {0,0,0,0};
  float4 wr0, wr1, wr2, wr3;

  {
    if (t < 192) {
      a0 = *(const float4*)&pt[a_row + a_q * 8];
      a1 = *(const float4*)&pt[a_row + a_q * 8 + 4];
    }
    const float* wb = w_base;
    wr0 = *(const float4*)&wb[(w_c +  0) * 4];
    wr1 = *(const float4*)&wb[(w_c +  8) * 4];
    wr2 = *(const float4*)&wb[(w_c + 16) * 4];
    wr3 = *(const float4*)&wb[(w_c + 24) * 4];
    if (t < 192) {
      #pragma unroll
      for (int j = 0; j < 4; ++j) {
        sA[0][a_q * 8 + j][a_tok]     = ((const float*)&a0)[j];
        sA[0][a_q * 8 + 4 + j][a_tok] = ((const float*)&a1)[j];
      }
    }
    *(float4*)&sW[0][w_r][(w_c +  0) * 4] = wr0;
    *(float4*)&sW[0][w_r][(w_c +  8) * 4] = wr1;
    *(float4*)&sW[0][w_r][(w_c + 16) * 4] = wr2;
    *(float4*)&sW[0][w_r][(w_c + 24) * 4] = wr3;
  }

  for (int s = 0; s < KSTEPS; ++s) {
    __syncthreads();
    int nb = s + 1;
    if (nb < KSTEPS) {
      int k0 = nb * BK;
      if (t < 192) {
        a0 = *(const float4*)&pt[a_row + k0 + a_q * 8];
        a1 = *(const float4*)&pt[a_row + k0 + a_q * 8 + 4];
      }
      const float* wb = w_base + (I64)k0 * HDIM;
      wr0 = *(const float4*)&wb[(w_c +  0) * 4];
      wr1 = *(const float4*)&wb[(w_c +  8) * 4];
      wr2 = *(const float4*)&wb[(w_c + 16) * 4];
      wr3 = *(const float4*)&wb[(w_c + 24) * 4];
    }
    int cur = s & 1;
    #pragma unroll 4
    for (int kk = 0; kk < BK; ++kk) {
      const float* ar = &sA[cur][kk][trow * 6];
      float2 a01 = *(const float2*)ar;
      float2 a23 = *(const float2*)(ar + 2);
      float2 a45 = *(const float2*)(ar + 4);
      float4 wv4 = *(const float4*)&sW[cur][kk][tcol * 4];
      float av[6] = {a01.x, a01.y, a23.x, a23.y, a45.x, a45.y};
      float wa[4] = {wv4.x, wv4.y, wv4.z, wv4.w};
      #pragma unroll
      for (int i = 0; i < 6; ++i)
        #pragma unroll
        for (int j = 0; j < 4; ++j)
          acc[i][j] = fmaf(av[i], wa[j], acc[i][j]);
    }
    if (nb < KSTEPS) {
      int nxt = nb & 1;
      if (t < 192) {
        #pragma unroll
        for (int j = 0; j < 4; ++j) {
          sA[nxt][a_q * 8 + j][a_tok]     = ((const float*)&a0)[j];
          sA[nxt][a_q * 8 + 4 + j][a_tok] = ((const float*)&a1)[j];
        }
      }
      *(float4*)&sW[nxt][w_r][(w_c +  0) * 4] = wr0;
      *(float4*)&sW[nxt][w_r][(w_c +  8) * 4] = wr1;
      *(float4*)&sW[nxt][w_r][(w_c + 16) * 4] = wr2;
      *(float4*)&sW[nxt][w_r][(w_c + 24) * 4] = wr3;
    }
  }

  int c = col0 + tcol * 4;
  float4 bv4 = *(const float4*)&bv[c];
  float4 bp4 = *(const float4*)&bp[c];
  float4 wp4 = *(const float4*)&Wp[c];
  float4 wo4 = *(const float4*)&Wo[c];
  float4 q4  = *(const float4*)&ws[WS_Q + (I64)b * HDIM + c];
  float bvv[4] = {bv4.x, bv4.y, bv4.z, bv4.w};
  float bpv[4] = {bp4.x, bp4.y, bp4.z, bp4.w};
  float wpv[4] = {wp4.x, wp4.y, wp4.z, wp4.w};
  float wov[4] = {wo4.x, wo4.y, wo4.z, wo4.w};
  float qv[4]  = {q4.x, q4.y, q4.z, q4.w};
  float partial[6];
  #pragma unroll
  for (int i = 0; i < 6; ++i) {
    float ppv = ws[WS_PP + b * GNUM + n0 + trow * 6 + i];
    float s = 0.f;
    #pragma unroll
    for (int j = 0; j < 4; ++j) {
      float pre = acc[i][j] + bvv[j] + bpv[j] + qv[j] + ppv * wpv[j];
      s = fmaf(wov[j], tanhf(pre), s);
    }
    partial[i] = s;
  }
  #pragma unroll
  for (int i = 0; i < 6; ++i) {
    float p = partial[i];
    p += __shfl_xor(p, 1);
    p += __shfl_xor(p, 2);
    p += __shfl_xor(p, 4);
    p += __shfl_xor(p, 8);
    p += __shfl_xor(p, 16);
    partial[i] = p;
  }
  if (tcol == 0) {
    #pragma unroll
    for (int i = 0; i < 6; ++i)
      ws[WS_RSP + ((I64)b * NTOK + n0 + trow * 6 + i) * 8 + ct] = partial[i];
  }
}

// ======================== K6: softmax + stable top-k ========================
__global__ __launch_bounds__(576) void k_soft(const float* __restrict__ bo,
                                              float* __restrict__ ws, float* __restrict__ out) {
  int b = blockIdx.x, t = threadIdx.x;
  __shared__ float s_rs[NTOK];
  __shared__ float s_w[9];
  __shared__ float s_max, s_sum;
  {
    const float* p = ws + WS_RSP + ((I64)b * NTOK + t) * 8;
    float s = bo[0];
    #pragma unroll
    for (int i = 0; i < 8; ++i) s += p[i];
    s_rs[t] = s;
  }
  __syncthreads();
  float v = s_rs[t];
  int r = 0;
  for (int j = 0; j < NTOK; ++j) {
    float vj = s_rs[j];
    r += (vj > v) || (vj == v && j < t);
  }
  float m = v;
  for (int off = 1; off < 64; off <<= 1) m = fmaxf(m, __shfl_xor(m, off));
  if ((t & 63) == 0) s_w[t >> 6] = m;
  __syncthreads();
  if (t == 0) {
    float mm = s_w[0];
    for (int i = 1; i < 9; ++i) mm = fmaxf(mm, s_w[i]);
    s_max = mm;
  }
  __syncthreads();
  float e = expf(v - s_max);
  float s = e;
  for (int off = 1; off < 64; off <<= 1) s += __shfl_xor(s, off);
  if ((t & 63) == 0) s_w[t >> 6] = s;
  __syncthreads();
  if (t == 0) {
    float ss = 0.f;
    for (int i = 0; i < 9; ++i) ss += s_w[i];
    s_sum = ss;
  }
  __syncthreads();
  out[OFF_RW + b * NTOK + t] = e / s_sum;
  if (r < CCTX) out[OFF_SEL + b * CCTX + r] = (float)t;
}

// ======================== K7: context gather + background (merged) ========================
// grid (CCTX+1, NB), 256 threads
__global__ __launch_bounds__(256) void k_post(const float* __restrict__ pt, const float* __restrict__ te,
                                              const float* __restrict__ ws, const float* __restrict__ outr,
                                              float* __restrict__ out) {
  int rr = blockIdx.x, b = blockIdx.y;
  int d = threadIdx.x * 4;
  if (rr < CCTX) {
    int idx = (int)outr[OFF_SEL + b * CCTX + rr];
    float4 v = *(const float4*)&pt[((I64)b * NTOK + idx) * DIM + d];
    float4 e = *(const float4*)&te[DIM + d];
    v.x += e.x; v.y += e.y; v.z += e.z; v.w += e.w;
    *(float4*)&out[OFF_CTX + ((I64)b * CCTX + rr) * DIM + d] = v;
    *(float4*)&out[OFF_VIS + ((I64)b * 161 + KREG + rr) * DIM + d] = v;
  } else {
    float4 s = *(const float4*)&ws[WS_CS + (I64)b * DIM + d];
    for (int r = 0; r < CCTX; ++r) {
      int idx = (int)outr[OFF_SEL + b * CCTX + r];
      float4 v = *(const float4*)&pt[((I64)b * NTOK + idx) * DIM + d];
      s.x -= v.x; s.y -= v.y; s.z -= v.z; s.w -= v.w;
    }
    const float rinv = 1.f / 448.f;
    float4 e = *(const float4*)&te[2 * DIM + d];
    float4 o;
    o.x = s.x * rinv + e.x; o.y = s.y * rinv + e.y;
    o.z = s.z * rinv + e.z; o.w = s.w * rinv + e.w;
    *(float4*)&out[OFF_BG + (I64)b * DIM + d] = o;
    *(float4*)&out[OFF_VIS + ((I64)b * 161 + 160) * DIM + d] = o;
  }
}

// ======================== launcher ========================
extern "C" void kernel_launch(void* const* d_in, const int* in_sizes, int n_in,
                              void* d_out, int out_size, void* d_ws, size_t ws_size,
                              hipStream_t stream) {
  (void)in_sizes; (void)n_in; (void)out_size; (void)ws_size;
  const float* pt     = (const float*)d_in[0];
  const float* masks  = (const float*)d_in[1];
  const float* scores = (const float*)d_in[2];
  const float* qe     = (const float*)d_in[3];
  const float* W1     = (const float*)d_in[4];
  const float* b1     = (const float*)d_in[5];
  const float* W2     = (const float*)d_in[6];
  const float* b2     = (const float*)d_in[7];
  const float* Wv     = (const float*)d_in[8];
  const float* bv     = (const float*)d_in[9];
  const float* Wp     = (const float*)d_in[10];
  const float* bp     = (const float*)d_in[11];
  const float* Wq     = (const float*)d_in[12];
  const float* bq     = (const float*)d_in[13];
  const float* Wo     = (const float*)d_in[14];
  const float* bo     = (const float*)d_in[15];
  const float* te     = (const float*)d_in[16];
  float* out = (float*)d_out;
  float* ws  = (float*)d_ws;

  k_bsq<<<dim3(BS_BLOCKS + 128), dim3(384), 0, stream>>>(masks, qe, Wq, bq, ws);
  k_perbatch<<<dim3(NB), dim3(256), 0, stream>>>(ws + WS_BS, scores, W1, b1, ws, out);
  k_region<<<dim3(512), dim3(512), 0, stream>>>(pt, W2, b2, te, ws, out);
  k_hid2<<<dim3(768), dim3(256), 0, stream>>>(pt, Wv, bv, Wp, bp, Wo, ws);
  k_soft<<<dim3(NB), dim3(576), 0, stream>>>(bo, ws, out);
  k_post<<<dim3(CCTX + 1, NB), dim3(256), 0, stream>>>(pt, te, ws, out, out);
}

// Round 5
// 375.641 us; speedup vs baseline: 1.6070x; 1.6070x over previous
//
#include <hip/hip_runtime.h>
#include <math.h>

typedef long long I64;

// ---- problem constants ----
#define NB    8
#define NTOK  576
#define DIM   1024
#define NMASK 64
#define HMASK 384
#define WMASK 384
#define QDIM  4096
#define HDIM  1024
#define KREG  32
#define CCTX  128
#define GH    24
#define GW    24
#define GNUM  576

// ---- output layout (floats) ----
#define OFF_VIS 0
#define OFF_REG 1318912
#define OFF_CTX 1581056
#define OFF_BG  2629632
#define OFF_PP  2637824
#define OFF_RW  2642432
#define OFF_SEL 2647040
#define OFF_GV  2648064

// ---- workspace layout (floats) ----
#define WS_BS   0          // B*M*576 block sums
#define WS_NMAT 294912     // B*32*576 normalized masks
#define WS_SCK  442368     // B*32 scores_k
#define WS_H1   442624     // B*32*1024 silu hidden
#define WS_Q    704768     // B*1024 question row partial (i<2048, +bq)
#define WS_GV   717568     // B grounding_valid
#define WS_PP   722184     // B*576 patch prior
#define WS_RSP  726792     // B*576*8 routing score partials
#define WS_CS   763656     // B*1024 token colsum
#define WS_Q2   771848     // B*1024 question row partial (i>=2048)
// total 780040 floats ~ 3.12 MB

#define QBLK      256                 // q-GEMV blocks: 8b x 16 colslices x 2 ihalves
#define BS_BLOCKS (NB * NMASK * 24)   // 12288

// ======================== K1: fused q-row GEMV (first) + mask block sums ========================
// blocks [0, QBLK): q partial = qe[b, ih*2048 : +2048] @ Wq[., 64-col slice]
//   384 thr = 64 d-lanes x 6 i-groups; qe half-row staged in LDS; 4 indep accumulators.
// blocks [QBLK, +BS_BLOCKS): one per (mask, 16-row band), fully coalesced 1KB/wave reads.
__global__ __launch_bounds__(384) void k_bsq(const float* __restrict__ masks,
                                             const float* __restrict__ qe,
                                             const float* __restrict__ Wq,
                                             const float* __restrict__ bq,
                                             float* __restrict__ ws) {
  int gid = blockIdx.x;
  int t = threadIdx.x;
  __shared__ float shm[2048 + 6 * 64];
  if (gid >= QBLK) {
    int gid2 = gid - QBLK;
    int yband = gid2 % 24;
    int bm = gid2 / 24;
    float (*sm)[96] = (float(*)[96])shm;
    const float4* src = (const float4*)(masks + (I64)bm * (HMASK * WMASK) + (I64)yband * 16 * WMASK);
    float4 s4 = src[t];
    float4 v1 = src[t + 384];
    float4 v2 = src[t + 768];
    float4 v3 = src[t + 1152];
    s4.x += v1.x; s4.y += v1.y; s4.z += v1.z; s4.w += v1.w;
    s4.x += v2.x; s4.y += v2.y; s4.z += v2.z; s4.w += v2.w;
    s4.x += v3.x; s4.y += v3.y; s4.z += v3.z; s4.w += v3.w;
    float s = (s4.x + s4.y) + (s4.z + s4.w);
    sm[t / 96][t % 96] = s;
    __syncthreads();
    if (t < 24) {
      float tt = 0.f;
      #pragma unroll
      for (int rg = 0; rg < 4; ++rg)
        #pragma unroll
        for (int c = 0; c < 4; ++c) tt += sm[rg][t * 4 + c];
      ws[WS_BS + (I64)bm * GNUM + yband * 24 + t] = tt;
    }
  } else {
    int b = gid >> 5;
    int r = gid & 31;
    int qb = r >> 1;           // 16 slices of 64 cols
    int ih = r & 1;            // i-half
    int base = ih * 2048;
    float* qs = shm;
    float (*sp)[64] = (float(*)[64])(shm + 2048);
    // stage qe half-row (2048 floats) into LDS
    {
      const float4* s4 = (const float4*)(qe + (I64)b * QDIM + base);
      float4 v = s4[t];
      *(float4*)&qs[t * 4] = v;
      if (t < 128) {
        float4 v2 = s4[t + 384];
        *(float4*)&qs[(t + 384) * 4] = v2;
      }
    }
    __syncthreads();
    int dl = t & 63, ig = t >> 6;
    int d = qb * 64 + dl;
    const float* wq = Wq + d;
    float a0 = 0.f, a1 = 0.f, a2 = 0.f, a3 = 0.f;
    int i = ig;
    for (; i + 18 < 2048; i += 24) {
      a0 = fmaf(qs[i],      wq[(I64)(base + i) * HDIM],      a0);
      a1 = fmaf(qs[i + 6],  wq[(I64)(base + i + 6) * HDIM],  a1);
      a2 = fmaf(qs[i + 12], wq[(I64)(base + i + 12) * HDIM], a2);
      a3 = fmaf(qs[i + 18], wq[(I64)(base + i + 18) * HDIM], a3);
    }
    for (; i < 2048; i += 6)
      a0 = fmaf(qs[i], wq[(I64)(base + i) * HDIM], a0);
    sp[ig][dl] = (a0 + a1) + (a2 + a3);
    __syncthreads();
    if (t < 64) {
      float s2 = ((sp[0][t] + sp[1][t]) + (sp[2][t] + sp[3][t])) + (sp[4][t] + sp[5][t]);
      int dd = qb * 64 + t;
      float outv = s2 + (ih ? 0.f : bq[dd]);
      ws[(ih ? WS_Q2 : WS_Q) + (I64)b * HDIM + dd] = outv;
    }
  }
}

// ======================== K2: per-batch small ops (LDS-staged) ========================
#define MGPAD 580
__global__ __launch_bounds__(256) void k_perbatch(
    const float* __restrict__ bs, const float* __restrict__ scores,
    const float* __restrict__ W1, const float* __restrict__ b1,
    float* __restrict__ ws, float* __restrict__ out) {
  int b = blockIdx.x;
  int t = threadIdx.x;
  __shared__ float s_mg[KREG][MGPAD];
  __shared__ float s_sc[NMASK];
  __shared__ float s_msum[NMASK];
  __shared__ int   s_order[NMASK];
  __shared__ float s_sck[KREG];
  __shared__ int   s_valid[KREG];
  __shared__ int   s_midx[KREG];
  __shared__ float s_rowsum[KREG];
  __shared__ float s_pp[GNUM];
  __shared__ float s_geom[KREG][5];
  __shared__ float s_red[64];
  __shared__ int   s_gv;
  __shared__ float s_ppsum;

  {
    int m = t >> 2, q = t & 3;
    const float4* p = (const float4*)(bs + ((I64)b * NMASK + m) * GNUM) + q * 36;
    float s = 0.f;
    #pragma unroll 4
    for (int j = 0; j < 36; ++j) {
      float4 v = p[j];
      s += v.x; s += v.y; s += v.z; s += v.w;
    }
    s += __shfl_xor(s, 1);
    s += __shfl_xor(s, 2);
    if (q == 0) s_msum[m] = s;
  }
  if (t < NMASK) s_sc[t] = scores[b * NMASK + t];
  __syncthreads();
  if (t == 0) {
    int g = 0;
    for (int m = 0; m < NMASK; ++m) g |= (s_msum[m] > 0.f) ? 1 : 0;
    s_gv = g;
  }
  if (t < NMASK) {
    float v = s_sc[t];
    int r = 0;
    for (int j = 0; j < NMASK; ++j) {
      float vj = s_sc[j];
      r += (vj > v) || (vj == v && j < t);
    }
    s_order[r] = t;
  }
  __syncthreads();
  const int gv = s_gv;
  if (t < KREG) {
    int m = s_order[t];
    float sc = s_sc[m];
    int valid = (sc >= 0.5f) ? 1 : 0;
    s_midx[t] = m;
    s_valid[t] = valid;
    float sck = gv ? (valid ? sc : 0.f) : 1.f;
    s_sck[t] = sck;
    ws[WS_SCK + b * KREG + t] = sck;
  }
  __syncthreads();
  {
    int k = t >> 3, sub = t & 7;
    const float inv256 = 1.f / 256.f;
    const float invN = 1.f / 576.f;
    float scale = gv ? (s_valid[k] ? inv256 : 0.f) : 0.f;
    float addv  = gv ? 0.f : invN;
    const float4* src = (const float4*)(bs + ((I64)b * NMASK + s_midx[k]) * GNUM) + sub * 18;
    float* dst = &s_mg[k][sub * 72];
    #pragma unroll 3
    for (int j = 0; j < 18; ++j) {
      float4 v = src[j];
      v.x = v.x * scale + addv;
      v.y = v.y * scale + addv;
      v.z = v.z * scale + addv;
      v.w = v.w * scale + addv;
      *(float4*)(dst + j * 4) = v;
    }
  }
  __syncthreads();
  {
    int k = t >> 3, sub = t & 7;
    float part = 0.f;
    for (int n = sub; n < GNUM; n += 8) part += fmaxf(s_mg[k][n], 0.f);
    part += __shfl_xor(part, 1);
    part += __shfl_xor(part, 2);
    part += __shfl_xor(part, 4);
    if (sub == 0) s_rowsum[k] = part;
  }
  __syncthreads();
  for (int idx = t; idx < KREG * GNUM; idx += 256) {
    int k = idx / GNUM, n = idx - k * GNUM;
    float v = fmaxf(s_mg[k][n], 0.f);
    ws[WS_NMAT + ((I64)b * KREG + k) * GNUM + n] = v / fmaxf(s_rowsum[k], 1e-6f);
  }
  for (int n = t; n < GNUM; n += 256) {
    float raw = 0.f;
    #pragma unroll
    for (int k = 0; k < KREG; ++k) raw = fmaf(s_mg[k][n], s_sck[k], raw);
    s_pp[n] = fmaxf(raw, 0.f);
  }
  __syncthreads();
  if (t < 64) {
    float s = 0.f;
    for (int n = t; n < GNUM; n += 64) s += s_pp[n];
    s_red[t] = s;
  }
  __syncthreads();
  if (t == 0) {
    float s = 0.f;
    for (int i = 0; i < 64; ++i) s += s_red[i];
    s_ppsum = s;
  }
  __syncthreads();
  {
    const float invN = 1.f / 576.f;
    float den = fmaxf(s_ppsum, 1e-6f);
    for (int n = t; n < GNUM; n += 256) {
      float v = gv ? (s_pp[n] / den) : invN;
      ws[WS_PP + b * GNUM + n] = v;
      out[OFF_PP + b * GNUM + n] = v;
    }
  }
  {
    int k = t >> 3, sub = t & 7;
    unsigned colmask = 0u;
    int ymin = GH, ymax = -1, cnt = 0;
    #pragma unroll
    for (int yy = 0; yy < 3; ++yy) {
      int y = sub * 3 + yy;
      unsigned rowm = 0u;
      for (int x = 0; x < GW; ++x)
        if (s_mg[k][y * GW + x] > 0.05f) rowm |= (1u << x);
      if (rowm) { if (y < ymin) ymin = y; if (y > ymax) ymax = y; }
      colmask |= rowm;
      cnt += __popc(rowm);
    }
    #pragma unroll
    for (int off = 1; off < 8; off <<= 1) {
      colmask |= (unsigned)__shfl_xor((int)colmask, off);
      cnt += __shfl_xor(cnt, off);
      int o1 = __shfl_xor(ymin, off); ymin = (o1 < ymin) ? o1 : ymin;
      int o2 = __shfl_xor(ymax, off); ymax = (o2 > ymax) ? o2 : ymax;
    }
    if (sub == 0) {
      float g0, g1, g2, g3, g4;
      if (cnt > 0) {
        int xmin = __ffs(colmask) - 1;
        int xmax = 31 - __clz(colmask);
        g0 = (float)xmin / 23.f;
        g1 = (float)ymin / 23.f;
        g2 = (float)xmax / 23.f;
        g3 = (float)ymax / 23.f;
        g4 = (float)cnt / 576.f;
      } else { g0 = g1 = g2 = g3 = g4 = 0.f; }
      s_geom[k][0] = g0; s_geom[k][1] = g1; s_geom[k][2] = g2;
      s_geom[k][3] = g3; s_geom[k][4] = g4;
    }
  }
  __syncthreads();
  for (int idx = t; idx < KREG * HDIM; idx += 256) {
    int k = idx >> 10, j = idx & 1023;
    float x = 0.f;
    #pragma unroll
    for (int i = 0; i < 5; ++i) x += s_geom[k][i] * W1[i * HDIM + j];
    x += b1[j];
    float sg = 1.f / (1.f + expf(-x));
    ws[WS_H1 + ((I64)b * KREG + k) * HDIM + j] = x * sg;
  }
  if (t == 0) {
    float g = gv ? 1.f : 0.f;
    ws[WS_GV + b] = g;
    out[OFF_GV + b] = g;
  }
}

// ======================== K4: region tokens + colsum (512 thr, 4 range-quarters) ========================
__global__ __launch_bounds__(512) void k_region(
    const float* __restrict__ pt, const float* __restrict__ W2,
    const float* __restrict__ b2, const float* __restrict__ te,
    float* __restrict__ ws, float* __restrict__ out) {
  int blk = blockIdx.x;
  int b = blk >> 6, kg = (blk >> 3) & 7, dg = blk & 7;
  int t = threadIdx.x;
  int dl = t & 127;
  int qh = t >> 7;
  int d = dg * 128 + dl;
  const float* nmb = ws + WS_NMAT + ((I64)b * KREG + kg * 4) * GNUM;
  const float* h1b = ws + WS_H1 + ((I64)b * KREG + kg * 4) * HDIM;
  float accP[4] = {0, 0, 0, 0};
  float accG[4] = {0, 0, 0, 0};
  float accS = 0.f;
  int n0 = qh * 144, n1 = n0 + 144;
  for (int n = n0; n < n1; ++n) {
    float p = pt[((I64)b * NTOK + n) * DIM + d];
    accS += p;
    #pragma unroll
    for (int kk = 0; kk < 4; ++kk)
      accP[kk] = fmaf(nmb[kk * GNUM + n], p, accP[kk]);
  }
  int j0 = qh * 256, j1 = j0 + 256;
  for (int j = j0; j < j1; ++j) {
    float wv = W2[(I64)j * DIM + d];
    #pragma unroll
    for (int kk = 0; kk < 4; ++kk)
      accG[kk] = fmaf(h1b[kk * HDIM + j], wv, accG[kk]);
  }
  __shared__ float cmbP[4][4][128];
  __shared__ float cmbG[4][4][128];
  __shared__ float cmbS[4][128];
  #pragma unroll
  for (int kk = 0; kk < 4; ++kk) {
    cmbP[qh][kk][dl] = accP[kk];
    cmbG[qh][kk][dl] = accG[kk];
  }
  cmbS[qh][dl] = accS;
  __syncthreads();
  if (qh == 0) {
    float bb = b2[d], t0 = te[d];
    #pragma unroll
    for (int kk = 0; kk < 4; ++kk) {
      int k = kg * 4 + kk;
      float P = (cmbP[0][kk][dl] + cmbP[1][kk][dl]) + (cmbP[2][kk][dl] + cmbP[3][kk][dl]);
      float G = (cmbG[0][kk][dl] + cmbG[1][kk][dl]) + (cmbG[2][kk][dl] + cmbG[3][kk][dl]);
      float val = P * ws[WS_SCK + b * KREG + k] + G + bb + t0;
      out[OFF_REG + ((I64)b * KREG + k) * DIM + d] = val;
      out[OFF_VIS + ((I64)b * 161 + k) * DIM + d] = val;
    }
    if (kg == 0)
      ws[WS_CS + (I64)b * DIM + d] =
          (cmbS[0][dl] + cmbS[1][dl]) + (cmbS[2][dl] + cmbS[3][dl]);
  }
}

// ======================== K5: fused hid GEMM ========================
#define BM 48
#define BN 128
#define BK 32
#define KSTEPS (DIM / BK)
__global__ __launch_bounds__(256) void k_hid2(
    const float* __restrict__ pt, const float* __restrict__ Wv,
    const float* __restrict__ bv, const float* __restrict__ Wp,
    const float* __restrict__ bp, const float* __restrict__ Wo,
    float* __restrict__ ws) {
  int blk = blockIdx.x;
  int b  = blk / 96;
  int r  = blk % 96;
  int tt = r >> 3;
  int ct = r & 7;
  int n0 = tt * BM;
  int col0 = ct * BN;
  int t = threadIdx.x;
  int tcol = t & 31;
  int trow = t >> 5;

  __shared__ float sA[2][BK][BM];
  __shared__ float sW[2][BK][BN];

  float acc[6][4];
  #pragma unroll
  for (int i = 0; i < 6; ++i)
    #pragma unroll
    for (int j = 0; j < 4; ++j) acc[i][j] = 0.f;

  int a_tok = t >> 2, a_q = t & 3;
  const I64 a_row = ((I64)b * NTOK + n0 + a_tok) * DIM;
  int w_r = t >> 3, w_c = t & 7;
  const float* w_base = Wv + (I64)w_r * HDIM + col0;

  float4 a0 = {0,0,0,0}, a1 = {0,0,0,0};
  float4 wr0, wr1, wr2, wr3;

  {
    if (t < 192) {
      a0 = *(const float4*)&pt[a_row + a_q * 8];
      a1 = *(const float4*)&pt[a_row + a_q * 8 + 4];
    }
    const float* wb = w_base;
    wr0 = *(const float4*)&wb[(w_c +  0) * 4];
    wr1 = *(const float4*)&wb[(w_c +  8) * 4];
    wr2 = *(const float4*)&wb[(w_c + 16) * 4];
    wr3 = *(const float4*)&wb[(w_c + 24) * 4];
    if (t < 192) {
      #pragma unroll
      for (int j = 0; j < 4; ++j) {
        sA[0][a_q * 8 + j][a_tok]     = ((const float*)&a0)[j];
        sA[0][a_q * 8 + 4 + j][a_tok] = ((const float*)&a1)[j];
      }
    }
    *(float4*)&sW[0][w_r][(w_c +  0) * 4] = wr0;
    *(float4*)&sW[0][w_r][(w_c +  8) * 4] = wr1;
    *(float4*)&sW[0][w_r][(w_c + 16) * 4] = wr2;
    *(float4*)&sW[0][w_r][(w_c + 24) * 4] = wr3;
  }

  for (int s = 0; s < KSTEPS; ++s) {
    __syncthreads();
    int nb = s + 1;
    if (nb < KSTEPS) {
      int k0 = nb * BK;
      if (t < 192) {
        a0 = *(const float4*)&pt[a_row + k0 + a_q * 8];
        a1 = *(const float4*)&pt[a_row + k0 + a_q * 8 + 4];
      }
      const float* wb = w_base + (I64)k0 * HDIM;
      wr0 = *(const float4*)&wb[(w_c +  0) * 4];
      wr1 = *(const float4*)&wb[(w_c +  8) * 4];
      wr2 = *(const float4*)&wb[(w_c + 16) * 4];
      wr3 = *(const float4*)&wb[(w_c + 24) * 4];
    }
    int cur = s & 1;
    #pragma unroll 4
    for (int kk = 0; kk < BK; ++kk) {
      const float* ar = &sA[cur][kk][trow * 6];
      float2 a01 = *(const float2*)ar;
      float2 a23 = *(const float2*)(ar + 2);
      float2 a45 = *(const float2*)(ar + 4);
      float4 wv4 = *(const float4*)&sW[cur][kk][tcol * 4];
      float av[6] = {a01.x, a01.y, a23.x, a23.y, a45.x, a45.y};
      float wa[4] = {wv4.x, wv4.y, wv4.z, wv4.w};
      #pragma unroll
      for (int i = 0; i < 6; ++i)
        #pragma unroll
        for (int j = 0; j < 4; ++j)
          acc[i][j] = fmaf(av[i], wa[j], acc[i][j]);
    }
    if (nb < KSTEPS) {
      int nxt = nb & 1;
      if (t < 192) {
        #pragma unroll
        for (int j = 0; j < 4; ++j) {
          sA[nxt][a_q * 8 + j][a_tok]     = ((const float*)&a0)[j];
          sA[nxt][a_q * 8 + 4 + j][a_tok] = ((const float*)&a1)[j];
        }
      }
      *(float4*)&sW[nxt][w_r][(w_c +  0) * 4] = wr0;
      *(float4*)&sW[nxt][w_r][(w_c +  8) * 4] = wr1;
      *(float4*)&sW[nxt][w_r][(w_c + 16) * 4] = wr2;
      *(float4*)&sW[nxt][w_r][(w_c + 24) * 4] = wr3;
    }
  }

  int c = col0 + tcol * 4;
  float4 bv4 = *(const float4*)&bv[c];
  float4 bp4 = *(const float4*)&bp[c];
  float4 wp4 = *(const float4*)&Wp[c];
  float4 wo4 = *(const float4*)&Wo[c];
  float4 q4a = *(const float4*)&ws[WS_Q  + (I64)b * HDIM + c];
  float4 q4b = *(const float4*)&ws[WS_Q2 + (I64)b * HDIM + c];
  float bvv[4] = {bv4.x, bv4.y, bv4.z, bv4.w};
  float bpv[4] = {bp4.x, bp4.y, bp4.z, bp4.w};
  float wpv[4] = {wp4.x, wp4.y, wp4.z, wp4.w};
  float wov[4] = {wo4.x, wo4.y, wo4.z, wo4.w};
  float qv[4]  = {q4a.x + q4b.x, q4a.y + q4b.y, q4a.z + q4b.z, q4a.w + q4b.w};
  float partial[6];
  #pragma unroll
  for (int i = 0; i < 6; ++i) {
    float ppv = ws[WS_PP + b * GNUM + n0 + trow * 6 + i];
    float s = 0.f;
    #pragma unroll
    for (int j = 0; j < 4; ++j) {
      float pre = acc[i][j] + bvv[j] + bpv[j] + qv[j] + ppv * wpv[j];
      s = fmaf(wov[j], tanhf(pre), s);
    }
    partial[i] = s;
  }
  #pragma unroll
  for (int i = 0; i < 6; ++i) {
    float p = partial[i];
    p += __shfl_xor(p, 1);
    p += __shfl_xor(p, 2);
    p += __shfl_xor(p, 4);
    p += __shfl_xor(p, 8);
    p += __shfl_xor(p, 16);
    partial[i] = p;
  }
  if (tcol == 0) {
    #pragma unroll
    for (int i = 0; i < 6; ++i)
      ws[WS_RSP + ((I64)b * NTOK + n0 + trow * 6 + i) * 8 + ct] = partial[i];
  }
}

// ======================== K6: softmax + stable top-k ========================
__global__ __launch_bounds__(576) void k_soft(const float* __restrict__ bo,
                                              float* __restrict__ ws, float* __restrict__ out) {
  int b = blockIdx.x, t = threadIdx.x;
  __shared__ float s_rs[NTOK];
  __shared__ float s_w[9];
  __shared__ float s_max, s_sum;
  {
    const float* p = ws + WS_RSP + ((I64)b * NTOK + t) * 8;
    float s = bo[0];
    #pragma unroll
    for (int i = 0; i < 8; ++i) s += p[i];
    s_rs[t] = s;
  }
  __syncthreads();
  float v = s_rs[t];
  int r = 0;
  for (int j = 0; j < NTOK; ++j) {
    float vj = s_rs[j];
    r += (vj > v) || (vj == v && j < t);
  }
  float m = v;
  for (int off = 1; off < 64; off <<= 1) m = fmaxf(m, __shfl_xor(m, off));
  if ((t & 63) == 0) s_w[t >> 6] = m;
  __syncthreads();
  if (t == 0) {
    float mm = s_w[0];
    for (int i = 1; i < 9; ++i) mm = fmaxf(mm, s_w[i]);
    s_max = mm;
  }
  __syncthreads();
  float e = expf(v - s_max);
  float s = e;
  for (int off = 1; off < 64; off <<= 1) s += __shfl_xor(s, off);
  if ((t & 63) == 0) s_w[t >> 6] = s;
  __syncthreads();
  if (t == 0) {
    float ss = 0.f;
    for (int i = 0; i < 9; ++i) ss += s_w[i];
    s_sum = ss;
  }
  __syncthreads();
  out[OFF_RW + b * NTOK + t] = e / s_sum;
  if (r < CCTX) out[OFF_SEL + b * CCTX + r] = (float)t;
}

// ======================== K7: context gather + background (merged) ========================
__global__ __launch_bounds__(256) void k_post(const float* __restrict__ pt, const float* __restrict__ te,
                                              const float* __restrict__ ws, const float* __restrict__ outr,
                                              float* __restrict__ out) {
  int rr = blockIdx.x, b = blockIdx.y;
  int d = threadIdx.x * 4;
  if (rr < CCTX) {
    int idx = (int)outr[OFF_SEL + b * CCTX + rr];
    float4 v = *(const float4*)&pt[((I64)b * NTOK + idx) * DIM + d];
    float4 e = *(const float4*)&te[DIM + d];
    v.x += e.x; v.y += e.y; v.z += e.z; v.w += e.w;
    *(float4*)&out[OFF_CTX + ((I64)b * CCTX + rr) * DIM + d] = v;
    *(float4*)&out[OFF_VIS + ((I64)b * 161 + KREG + rr) * DIM + d] = v;
  } else {
    float4 s = *(const float4*)&ws[WS_CS + (I64)b * DIM + d];
    for (int r = 0; r < CCTX; ++r) {
      int idx = (int)outr[OFF_SEL + b * CCTX + r];
      float4 v = *(const float4*)&pt[((I64)b * NTOK + idx) * DIM + d];
      s.x -= v.x; s.y -= v.y; s.z -= v.z; s.w -= v.w;
    }
    const float rinv = 1.f / 448.f;
    float4 e = *(const float4*)&te[2 * DIM + d];
    float4 o;
    o.x = s.x * rinv + e.x; o.y = s.y * rinv + e.y;
    o.z = s.z * rinv + e.z; o.w = s.w * rinv + e.w;
    *(float4*)&out[OFF_BG + (I64)b * DIM + d] = o;
    *(float4*)&out[OFF_VIS + ((I64)b * 161 + 160) * DIM + d] = o;
  }
}

// ======================== launcher ========================
extern "C" void kernel_launch(void* const* d_in, const int* in_sizes, int n_in,
                              void* d_out, int out_size, void* d_ws, size_t ws_size,
                              hipStream_t stream) {
  (void)in_sizes; (void)n_in; (void)out_size; (void)ws_size;
  const float* pt     = (const float*)d_in[0];
  const float* masks  = (const float*)d_in[1];
  const float* scores = (const float*)d_in[2];
  const float* qe     = (const float*)d_in[3];
  const float* W1     = (const float*)d_in[4];
  const float* b1     = (const float*)d_in[5];
  const float* W2     = (const float*)d_in[6];
  const float* b2     = (const float*)d_in[7];
  const float* Wv     = (const float*)d_in[8];
  const float* bv     = (const float*)d_in[9];
  const float* Wp     = (const float*)d_in[10];
  const float* bp     = (const float*)d_in[11];
  const float* Wq     = (const float*)d_in[12];
  const float* bq     = (const float*)d_in[13];
  const float* Wo     = (const float*)d_in[14];
  const float* bo     = (const float*)d_in[15];
  const float* te     = (const float*)d_in[16];
  float* out = (float*)d_out;
  float* ws  = (float*)d_ws;

  k_bsq<<<dim3(QBLK + BS_BLOCKS), dim3(384), 0, stream>>>(masks, qe, Wq, bq, ws);
  k_perbatch<<<dim3(NB), dim3(256), 0, stream>>>(ws + WS_BS, scores, W1, b1, ws, out);
  k_region<<<dim3(512), dim3(512), 0, stream>>>(pt, W2, b2, te, ws, out);
  k_hid2<<<dim3(768), dim3(256), 0, stream>>>(pt, Wv, bv, Wp, bp, Wo, ws);
  k_soft<<<dim3(NB), dim3(576), 0, stream>>>(bo, ws, out);
  k_post<<<dim3(CCTX + 1, NB), dim3(256), 0, stream>>>(pt, te, ws, out, out);
}